// Round 4
// baseline (3420.379 us; speedup 1.0000x reference)
//
#include <hip/hip_runtime.h>
#include <cstdint>

typedef __attribute__((ext_vector_type(8))) short short8;            // 8 bf16 = 4 VGPRs
typedef __attribute__((ext_vector_type(4))) float floatx4;           // MFMA C/D

__device__ __forceinline__ unsigned short f32_to_bf16_rne(float f) {
  uint32_t u = __float_as_uint(f);
  u += 0x7FFFu + ((u >> 16) & 1u);   // RNE (inputs finite normals)
  return (unsigned short)(u >> 16);
}

__device__ __forceinline__ ushort4 cvt4_f(float4 v) {
  ushort4 r;
  r.x = f32_to_bf16_rne(v.x); r.y = f32_to_bf16_rne(v.y);
  r.z = f32_to_bf16_rne(v.z); r.w = f32_to_bf16_rne(v.w);
  return r;
}
__device__ __forceinline__ ushort4 cvt4_i(int4 v) {
  ushort4 r;
  r.x = (unsigned short)(__float_as_uint((float)v.x) >> 16);
  r.y = (unsigned short)(__float_as_uint((float)v.y) >> 16);
  r.z = (unsigned short)(__float_as_uint((float)v.z) >> 16);
  r.w = (unsigned short)(__float_as_uint((float)v.w) >> 16);
  return r;
}

// Fused conversion (unchanged, verified): x fp32->bf16 RNE, w int32->bf16 (exact).
__global__ void cvt_fused(const float4* __restrict__ x, const int4* __restrict__ w,
                          ushort4* __restrict__ ox, ushort4* __restrict__ ow, int nbx) {
  const int t = threadIdx.x;
  if ((int)blockIdx.x < nbx) {
    const int base = blockIdx.x * 512;
    float4 a = x[base + t];
    float4 b = x[base + 256 + t];
    ox[base + t]       = cvt4_f(a);
    ox[base + 256 + t] = cvt4_f(b);
  } else {
    const int base = ((int)blockIdx.x - nbx) * 512;
    int4 a = w[base + t];
    int4 b = w[base + 256 + t];
    ow[base + t]       = cvt4_i(a);
    ow[base + 256 + t] = cvt4_i(b);
  }
}

__device__ __forceinline__ void async16(const void* g, void* l) {
  __builtin_amdgcn_global_load_lds((__attribute__((address_space(1))) void*)(g),
                                   (__attribute__((address_space(3))) void*)(l), 16, 0, 0);
}

#define BARRIER() asm volatile("s_barrier" ::: "memory")

// 256x256 tile, BK=32, 4-deep LDS ring (128 KB), 8 waves (2x4), wave tile 128x64.
// R4: ANTI-PHASE wave roles. Per inter-barrier interval, group A waves run
// {ds_reads -> MFMA} while group B waves run {MFMA -> ds_reads} on one-phase-lag
// fragments. Group parity (wv ^ (wv>>2)) & 1 anti-pairs the two waves of every
// SIMD under both plausible wave->SIMD mappings, so the LDS pipe and matrix pipe
// are both fed from t=0 of every interval (m114 co-scheduling).
// Sync ledger:
//  - ONE counted vmcnt per K-tile (mid-tile): vmcnt(6) forces tile kt+1 landed
//    before phase 1 reads it (in-flight: kt+2's 4 + kt+3's A-half 2). Tail 4->0.
//  - Ring reuse: stage in phase 0 of kt+1 targets slot kt; every read of slot kt
//    is consumed by an MFMA issued before the tile-end barrier (in-order DS +
//    operand waits), so all waves' slot-kt reads are complete when any wave
//    passes that barrier. In-flight reads at the barrier target slot kt+1 only.
__global__ __launch_bounds__(512, 2) void gemm256_bt_bf16(
    const unsigned short* __restrict__ A, const unsigned short* __restrict__ B,
    const float* __restrict__ scale, const float* __restrict__ bias,
    float* __restrict__ C, int M, int N, int K) {
  constexpr int BM = 256, BN = 256, BK = 32;
  constexpr int ABK = BM * BK;            // 8192 ushorts: B half starts here
  constexpr int BUFSZ = (BM + BN) * BK;   // 16384 ushorts = 32 KB / ring slot
  __shared__ __align__(16) unsigned short lds[4 * BUFSZ];  // 128 KB

  const int tid  = threadIdx.x;
  const int lane = tid & 63;
  const int wv   = tid >> 6;   // 8 waves
  const int wm   = wv >> 2;    // 0..1 -> 128 rows each
  const int wn   = wv & 3;     // 0..3 -> 64 cols each
  const bool ga  = ((wv ^ (wv >> 2)) & 1) == 0;   // anti-phase group

  // T1: XCD-aware block swizzle (bijective; gridDim.x % 8 == 0 here)
  const int nwg = gridDim.x;
  const int bid = blockIdx.x;
  const int swz = ((nwg & 7) == 0) ? ((bid & 7) * (nwg >> 3) + (bid >> 3)) : bid;
  const int ntn = N / BN;
  const int tm = swz / ntn, tn = swz - tm * ntn;
  const int aM = tm * BM, bN = tn * BN;

  // staging: 256 rows x 4 segs(16B) per matrix = 1024 slots; thread t owns
  // slots t and t+512. physical slot p holds logical seg (p&3)^((row>>1)&3).
  const int t0 = tid, t1 = tid + 512;
  const int r0 = t0 >> 2, s0 = (t0 & 3) ^ ((r0 >> 1) & 3);
  const int r1 = t1 >> 2, s1 = (t1 & 3) ^ ((r1 >> 1) & 3);
  const unsigned short* gA0 = A + (size_t)(aM + r0) * K + s0 * 8;
  const unsigned short* gA1 = A + (size_t)(aM + r1) * K + s1 * 8;
  const unsigned short* gB0 = B + (size_t)(bN + r0) * K + s0 * 8;
  const unsigned short* gB1 = B + (size_t)(bN + r1) * K + s1 * 8;

  // frag reads: A[m=row16][k=quad*8+j], physical seg = quad ^ ((row>>1)&3)
  // (verified conflict-free: SQ_LDS_BANK_CONFLICT == 0)
  const int row16 = lane & 15;
  const int quad  = lane >> 4;
  const int seg   = (quad ^ ((row16 >> 1) & 3)) * 8;
  const int offA  = (wm * 128 + row16) * BK + seg;        // + i*16*BK
  const int offB  = ABK + (wn * 64 + row16) * BK + seg;   // + j*16*BK

  floatx4 acc[8][4] = {};
  const int NT = K / BK;   // even (K % 64 == 0 gated by dispatcher)

  // prologue: stage K-tiles 0..2 into ring slots 0..2 (12 loads/thread)
#pragma unroll
  for (int p = 0; p < 3; ++p) {
    unsigned short* d = lds + p * BUFSZ;
    const int ko = p * BK;
    async16(gA0 + ko, d + t0 * 8);
    async16(gA1 + ko, d + t1 * 8);
    async16(gB0 + ko, d + ABK + t0 * 8);
    async16(gB1 + ko, d + ABK + t1 * 8);
  }
  asm volatile("s_waitcnt vmcnt(8)" ::: "memory");  // tile 0 landed (own 4 loads)
  BARRIER();                                        // cross-wave: tile 0 visible

#define RD_NEXT(b, AF, BF)                                                     \
  _Pragma("unroll") for (int t = 0; t < 4; ++t) {                              \
    AF[t] = *(const short8*)((b) + offA + t * 16 * BK);                        \
    BF[t] = *(const short8*)((b) + offB + t * 16 * BK);                        \
  }
#define RD_AG(b, AG)                                                           \
  _Pragma("unroll") for (int t = 0; t < 4; ++t)                                \
    AG[t] = *(const short8*)((b) + offA + (t + 4) * 16 * BK);
#define MFMA_C0(AF, BF)                                                        \
  __builtin_amdgcn_s_setprio(1);                                              \
  _Pragma("unroll") for (int i = 0; i < 4; ++i)                                \
    _Pragma("unroll") for (int j = 0; j < 4; ++j)                              \
      acc[i][j] = __builtin_amdgcn_mfma_f32_16x16x32_bf16(AF[i], BF[j],        \
                                                          acc[i][j], 0, 0, 0); \
  __builtin_amdgcn_s_setprio(0);
#define MFMA_C1(AG, BF)                                                        \
  __builtin_amdgcn_s_setprio(1);                                              \
  _Pragma("unroll") for (int i = 0; i < 4; ++i)                                \
    _Pragma("unroll") for (int j = 0; j < 4; ++j)                              \
      acc[i + 4][j] = __builtin_amdgcn_mfma_f32_16x16x32_bf16(AG[i], BF[j],    \
                                                      acc[i + 4][j], 0, 0, 0); \
  __builtin_amdgcn_s_setprio(0);
#define STAGE_A(dst, ko)                                                       \
  { async16(gA0 + (ko), (dst) + t0 * 8); async16(gA1 + (ko), (dst) + t1 * 8); }
#define STAGE_B(dst, ko)                                                       \
  { async16(gB0 + (ko), (dst) + ABK + t0 * 8); async16(gB1 + (ko), (dst) + ABK + t1 * 8); }

  // mid-tile counted vmcnt: tile kt+1 landed before phase 1 reads it
#define VMCNT_MID(kt)                                                          \
  if ((kt) <= NT - 4)      asm volatile("s_waitcnt vmcnt(6)" ::: "memory");    \
  else if ((kt) == NT - 3) asm volatile("s_waitcnt vmcnt(4)" ::: "memory");    \
  else if ((kt) == NT - 2) asm volatile("s_waitcnt vmcnt(0)" ::: "memory");

#define TILE(kt, AF, BF, NAF, NBF)                                             \
  {                                                                            \
    const unsigned short* buf  = lds + ((kt) & 3) * BUFSZ;                     \
    const unsigned short* nbuf = lds + (((kt) + 1) & 3) * BUFSZ;               \
    unsigned short* dst = lds + (((kt) + 3) & 3) * BUFSZ;                      \
    const int ko = ((kt) + 3) * BK;                                            \
    const bool pf = ((kt) + 3) < NT;                                           \
    short8 ag[4];                                                              \
    /* ---- phase 0: acc rows 0-3 (reads: A4-7 of kt) ---- */                  \
    if (ga) {                                                                  \
      RD_AG(buf, ag);                                                          \
      if (pf) STAGE_A(dst, ko);                                                \
      __builtin_amdgcn_sched_barrier(0);                                       \
      MFMA_C0(AF, BF);                                                         \
    } else {                                                                   \
      MFMA_C0(AF, BF);                                                         \
      __builtin_amdgcn_sched_barrier(0);                                       \
      RD_AG(buf, ag);                                                          \
      if (pf) STAGE_A(dst, ko);                                                \
    }                                                                          \
    VMCNT_MID(kt);                                                             \
    BARRIER();                                                                 \
    /* ---- phase 1: acc rows 4-7 (reads: A0-3 + B of kt+1) ---- */            \
    if (ga) {                                                                  \
      if ((kt) + 1 < NT) RD_NEXT(nbuf, NAF, NBF);                              \
      if (pf) STAGE_B(dst, ko);                                                \
      __builtin_amdgcn_sched_barrier(0);                                       \
      MFMA_C1(ag, BF);                                                         \
    } else {                                                                   \
      MFMA_C1(ag, BF);                                                         \
      __builtin_amdgcn_sched_barrier(0);                                       \
      if ((kt) + 1 < NT) RD_NEXT(nbuf, NAF, NBF);                              \
      if (pf) STAGE_B(dst, ko);                                                \
    }                                                                          \
    BARRIER();                                                                 \
  }

  short8 afX[4], bfX[4], afY[4], bfY[4];
  RD_NEXT(lds, afX, bfX);   // tile 0, phase-0 fragments (slot 0)

  for (int kt = 0; kt < NT; kt += 2) {
    TILE(kt,     afX, bfX, afY, bfY);
    TILE(kt + 1, afY, bfY, afX, bfX);
  }
#undef TILE
#undef VMCNT_MID
#undef STAGE_A
#undef STAGE_B
#undef MFMA_C0
#undef MFMA_C1
#undef RD_AG
#undef RD_NEXT

  // --- epilogue: C/D layout col=lane&15, row=(lane>>4)*4+reg (m89-verified)
#pragma unroll
  for (int j = 0; j < 4; ++j) {
    const int n = bN + wn * 64 + j * 16 + row16;
    const float s = scale[n];
    const float b = bias[n];
#pragma unroll
    for (int i = 0; i < 8; ++i) {
      const int m0 = aM + wm * 128 + i * 16 + quad * 4;
      floatx4 c = acc[i][j];
      C[(size_t)(m0 + 0) * N + n] = c[0] * s + b;
      C[(size_t)(m0 + 1) * N + n] = c[1] * s + b;
      C[(size_t)(m0 + 2) * N + n] = c[2] * s + b;
      C[(size_t)(m0 + 3) * N + n] = c[3] * s + b;
    }
  }
}

// Insurance only: used if shapes/ws don't fit the fast path.
__global__ void naive_kernel(const float* __restrict__ x, const int* __restrict__ w,
                             const float* __restrict__ s, const float* __restrict__ b,
                             float* __restrict__ y, int M, int N, int K) {
  int n = blockIdx.x * blockDim.x + threadIdx.x;
  int m = blockIdx.y;
  if (n >= N) return;
  float acc = 0.f;
  for (int k = 0; k < K; ++k) acc += x[(size_t)m * K + k] * (float)w[(size_t)n * K + k];
  y[(size_t)m * N + n] = acc * s[n] + b[n];
}

extern "C" void kernel_launch(void* const* d_in, const int* in_sizes, int n_in,
                              void* d_out, int out_size, void* d_ws, size_t ws_size,
                              hipStream_t stream) {
  const float* x     = (const float*)d_in[0];
  const int*   wq    = (const int*)d_in[1];
  const float* scale = (const float*)d_in[2];
  const float* bias  = (const float*)d_in[3];
  float* y = (float*)d_out;

  const int xN = in_sizes[0];           // M*K
  const int wN = in_sizes[1];           // N*K
  const int N  = in_sizes[2];           // D_OUT
  const int K  = wN / N;
  const int M  = xN / K;

  const size_t need = (size_t)xN * 2 + (size_t)wN * 2;  // 96 MiB here
  if (ws_size >= need && (M % 256) == 0 && (N % 256) == 0 && (K % 64) == 0 &&
      K >= 256 && (xN % 2048) == 0 && (wN % 2048) == 0) {
    unsigned short* xb = (unsigned short*)d_ws;
    unsigned short* wb = xb + (size_t)xN;
    const int nbx = xN / 2048, nbw = wN / 2048;
    cvt_fused<<<nbx + nbw, 256, 0, stream>>>((const float4*)x, (const int4*)wq,
                                             (ushort4*)xb, (ushort4*)wb, nbx);
    const int nwg = (M / 256) * (N / 256);
    gemm256_bt_bf16<<<nwg, 512, 0, stream>>>(xb, wb, scale, bias, y, M, N, K);
  } else {
    dim3 grid((N + 255) / 256, M);
    naive_kernel<<<grid, 256, 0, stream>>>(x, wq, scale, bias, y, M, N, K);
  }
}

// Round 5
// 529.734 us; speedup vs baseline: 6.4568x; 6.4568x over previous
//
#include <hip/hip_runtime.h>
#include <cstdint>

typedef __attribute__((ext_vector_type(8))) short short8;            // 8 bf16 = 4 VGPRs
typedef __attribute__((ext_vector_type(16))) float floatx16;         // 32x32 MFMA C/D

__device__ __forceinline__ unsigned short f32_to_bf16_rne(float f) {
  uint32_t u = __float_as_uint(f);
  u += 0x7FFFu + ((u >> 16) & 1u);   // RNE (inputs finite normals)
  return (unsigned short)(u >> 16);
}

__device__ __forceinline__ ushort4 cvt4_f(float4 v) {
  ushort4 r;
  r.x = f32_to_bf16_rne(v.x); r.y = f32_to_bf16_rne(v.y);
  r.z = f32_to_bf16_rne(v.z); r.w = f32_to_bf16_rne(v.w);
  return r;
}
__device__ __forceinline__ ushort4 cvt4_i(int4 v) {
  ushort4 r;
  r.x = (unsigned short)(__float_as_uint((float)v.x) >> 16);
  r.y = (unsigned short)(__float_as_uint((float)v.y) >> 16);
  r.z = (unsigned short)(__float_as_uint((float)v.z) >> 16);
  r.w = (unsigned short)(__float_as_uint((float)v.w) >> 16);
  return r;
}

// Fused conversion (unchanged, verified): x fp32->bf16 RNE, w int32->bf16 (exact).
__global__ void cvt_fused(const float4* __restrict__ x, const int4* __restrict__ w,
                          ushort4* __restrict__ ox, ushort4* __restrict__ ow, int nbx) {
  const int t = threadIdx.x;
  if ((int)blockIdx.x < nbx) {
    const int base = blockIdx.x * 512;
    float4 a = x[base + t];
    float4 b = x[base + 256 + t];
    ox[base + t]       = cvt4_f(a);
    ox[base + 256 + t] = cvt4_f(b);
  } else {
    const int base = ((int)blockIdx.x - nbx) * 512;
    int4 a = w[base + t];
    int4 b = w[base + 256 + t];
    ow[base + t]       = cvt4_i(a);
    ow[base + 256 + t] = cvt4_i(b);
  }
}

__device__ __forceinline__ void async16(const void* g, void* l) {
  __builtin_amdgcn_global_load_lds((__attribute__((address_space(1))) void*)(g),
                                   (__attribute__((address_space(3))) void*)(l), 16, 0, 0);
}

#define BARRIER() asm volatile("s_barrier" ::: "memory")
#define LGKM0()   do { asm volatile("s_waitcnt lgkmcnt(0)" ::: "memory"); \
                       __builtin_amdgcn_sched_barrier(0); } while (0)

// 256x256 tile, BK=32, 4-deep LDS ring (128 KB), 8 waves (2x4), wave tile 128x64.
// R5: R3's verified schedule skeleton (ring-4 staging, counted vmcnt once per
// K-tile, 2 phases x {reads; stage; barrier; lgkm0; MFMA cluster; barrier}),
// with the MFMA shape switched 16x16x32 -> 32x32x16 (m119: 2495 vs 2075 TF
// ceiling = 17% lower compute floor, same LDS bytes, half the instructions).
// Race ledger identical to R3 (staging layout and sync points unchanged).
__global__ __launch_bounds__(512, 2) void gemm256_bt_bf16(
    const unsigned short* __restrict__ A, const unsigned short* __restrict__ B,
    const float* __restrict__ scale, const float* __restrict__ bias,
    float* __restrict__ C, int M, int N, int K) {
  constexpr int BM = 256, BN = 256, BK = 32;
  constexpr int ABK = BM * BK;            // 8192 ushorts: B half starts here
  constexpr int BUFSZ = (BM + BN) * BK;   // 16384 ushorts = 32 KB / ring slot
  __shared__ __align__(16) unsigned short lds[4 * BUFSZ];  // 128 KB

  const int tid  = threadIdx.x;
  const int lane = tid & 63;
  const int wv   = tid >> 6;   // 8 waves
  const int wm   = wv >> 2;    // 0..1 -> 128 rows each
  const int wn   = wv & 3;     // 0..3 -> 64 cols each

  // T1: XCD-aware block swizzle (bijective; gridDim.x % 8 == 0 here)
  const int nwg = gridDim.x;
  const int bid = blockIdx.x;
  const int swz = ((nwg & 7) == 0) ? ((bid & 7) * (nwg >> 3) + (bid >> 3)) : bid;
  const int ntn = N / BN;
  const int tm = swz / ntn, tn = swz - tm * ntn;
  const int aM = tm * BM, bN = tn * BN;

  // staging: 256 rows x 4 segs(16B) per matrix = 1024 slots; thread t owns
  // slots t and t+512. physical slot p holds logical seg (p&3)^((row>>1)&3).
  // (unchanged from R3 -- verified conflict-free, SQ_LDS_BANK_CONFLICT == 0)
  const int t0 = tid, t1 = tid + 512;
  const int r0 = t0 >> 2, s0 = (t0 & 3) ^ ((r0 >> 1) & 3);
  const int r1 = t1 >> 2, s1 = (t1 & 3) ^ ((r1 >> 1) & 3);
  const unsigned short* gA0 = A + (size_t)(aM + r0) * K + s0 * 8;
  const unsigned short* gA1 = A + (size_t)(aM + r1) * K + s1 * 8;
  const unsigned short* gB0 = B + (size_t)(bN + r0) * K + s0 * 8;
  const unsigned short* gB1 = B + (size_t)(bN + r1) * K + s1 * 8;

  // 32x32x16 fragment reads: lane holds X[row32 = lane&31][k = kh*8 + e],
  // kh = lane>>5. For k-step ks (0/1): logical 16B-seg s = ks*2 + kh (0..3),
  // physical seg = s ^ ((row32>>1)&3)  [wm*128 / mt*32 / wn*64 / nt*32 row
  // offsets contribute 0 to ((row>>1)&3), so only row32 matters].
  // Bank check: lanes 0..7 (rows 0..7, fixed s) hit 8 distinct 4-bank groups;
  // 16-lane granularity -> 2-way aliasing = free (m136).
  const int row32 = lane & 31;
  const int kh    = lane >> 5;
  const int sw32  = (row32 >> 1) & 3;
  // A: m-tile mt (0..3, 32 rows each), k-step ks (0..1)
  const int baseA = (wm * 128 + row32) * BK;         // + mt*32*BK + physseg*8
  const int baseB = ABK + (wn * 64 + row32) * BK;    // + nt*32*BK + physseg*8

  floatx16 acc[4][2] = {};
  const int NT = K / BK;

  // prologue: stage K-tiles 0..2 into ring slots 0..2 (12 loads/thread)
#pragma unroll
  for (int p = 0; p < 3; ++p) {
    unsigned short* d = lds + p * BUFSZ;
    const int ko = p * BK;
    async16(gA0 + ko, d + t0 * 8);
    async16(gA1 + ko, d + t1 * 8);
    async16(gB0 + ko, d + ABK + t0 * 8);
    async16(gB1 + ko, d + ABK + t1 * 8);
  }
  asm volatile("s_waitcnt vmcnt(8)" ::: "memory");  // tile 0 landed (own 4 loads)
  BARRIER();                                        // cross-wave: tile 0 visible

  for (int kt = 0; kt < NT; ++kt) {
    const unsigned short* buf = lds + (kt & 3) * BUFSZ;
    unsigned short* dst = lds + ((kt + 3) & 3) * BUFSZ;   // == (kt-1)&3, freed
    const int ko = (kt + 3) * BK;
    const bool pf = (kt + 3) < NT;

    // ============ phase A: acc m-tiles 0-1 (8 MFMA) ============
    short8 af[2][2], bf[2][2];   // [mt][ks], [nt][ks]
#pragma unroll
    for (int mt = 0; mt < 2; ++mt)
#pragma unroll
      for (int ks = 0; ks < 2; ++ks) {
        const int ps = ((ks * 2 + kh) ^ sw32) * 8;
        af[mt][ks] = *(const short8*)(buf + baseA + mt * 32 * BK + ps);
        bf[mt][ks] = *(const short8*)(buf + baseB + mt * 32 * BK + ps);  // mt as nt
      }
    if (pf) {  // stage half-tile: A-rows of tile kt+3
      async16(gA0 + ko, dst + t0 * 8);
      async16(gA1 + ko, dst + t1 * 8);
    }
    BARRIER();
    LGKM0();
    __builtin_amdgcn_s_setprio(1);
#pragma unroll
    for (int ks = 0; ks < 2; ++ks)
#pragma unroll
      for (int i = 0; i < 2; ++i)
#pragma unroll
        for (int j = 0; j < 2; ++j)
          acc[i][j] = __builtin_amdgcn_mfma_f32_32x32x16_bf16(af[i][ks], bf[j][ks],
                                                              acc[i][j], 0, 0, 0);
    __builtin_amdgcn_s_setprio(0);
    BARRIER();

    // ============ phase B: acc m-tiles 2-3 (8 MFMA) ============
    short8 ag[2][2];
#pragma unroll
    for (int mt = 0; mt < 2; ++mt)
#pragma unroll
      for (int ks = 0; ks < 2; ++ks) {
        const int ps = ((ks * 2 + kh) ^ sw32) * 8;
        ag[mt][ks] = *(const short8*)(buf + baseA + (mt + 2) * 32 * BK + ps);
      }
    if (pf) {  // stage half-tile: B-rows of tile kt+3
      async16(gB0 + ko, dst + ABK + t0 * 8);
      async16(gB1 + ko, dst + ABK + t1 * 8);
    }
    // counted vmcnt, once per K-tile: next iter reads tile kt+1
    if (kt <= NT - 4)      asm volatile("s_waitcnt vmcnt(8)" ::: "memory");
    else if (kt == NT - 3) asm volatile("s_waitcnt vmcnt(4)" ::: "memory");
    else if (kt == NT - 2) asm volatile("s_waitcnt vmcnt(0)" ::: "memory");
    BARRIER();
    LGKM0();
    __builtin_amdgcn_s_setprio(1);
#pragma unroll
    for (int ks = 0; ks < 2; ++ks)
#pragma unroll
      for (int i = 0; i < 2; ++i)
#pragma unroll
        for (int j = 0; j < 2; ++j)
          acc[i + 2][j] = __builtin_amdgcn_mfma_f32_32x32x16_bf16(ag[i][ks], bf[j][ks],
                                                                  acc[i + 2][j], 0, 0, 0);
    __builtin_amdgcn_s_setprio(0);
    BARRIER();
  }

  // --- epilogue: 32x32 C/D layout col=lane&31, row=(reg&3)+8*(reg>>2)+4*(lane>>5)
  // (m74/m101-verified, dtype-independent)
#pragma unroll
  for (int j = 0; j < 2; ++j) {
    const int n = bN + wn * 64 + j * 32 + row32;
    const float s = scale[n];
    const float b = bias[n];
#pragma unroll
    for (int i = 0; i < 4; ++i) {
      const int mb = aM + wm * 128 + i * 32 + kh * 4;
      floatx16 c = acc[i][j];
#pragma unroll
      for (int rg = 0; rg < 16; ++rg) {
        const int m = mb + (rg & 3) + 8 * (rg >> 2);
        C[(size_t)m * N + n] = c[rg] * s + b;
      }
    }
  }
}

// Insurance only: used if shapes/ws don't fit the fast path.
__global__ void naive_kernel(const float* __restrict__ x, const int* __restrict__ w,
                             const float* __restrict__ s, const float* __restrict__ b,
                             float* __restrict__ y, int M, int N, int K) {
  int n = blockIdx.x * blockDim.x + threadIdx.x;
  int m = blockIdx.y;
  if (n >= N) return;
  float acc = 0.f;
  for (int k = 0; k < K; ++k) acc += x[(size_t)m * K + k] * (float)w[(size_t)n * K + k];
  y[(size_t)m * N + n] = acc * s[n] + b[n];
}

extern "C" void kernel_launch(void* const* d_in, const int* in_sizes, int n_in,
                              void* d_out, int out_size, void* d_ws, size_t ws_size,
                              hipStream_t stream) {
  const float* x     = (const float*)d_in[0];
  const int*   wq    = (const int*)d_in[1];
  const float* scale = (const float*)d_in[2];
  const float* bias  = (const float*)d_in[3];
  float* y = (float*)d_out;

  const int xN = in_sizes[0];           // M*K
  const int wN = in_sizes[1];           // N*K
  const int N  = in_sizes[2];           // D_OUT
  const int K  = wN / N;
  const int M  = xN / K;

  const size_t need = (size_t)xN * 2 + (size_t)wN * 2;  // 96 MiB here
  if (ws_size >= need && (M % 256) == 0 && (N % 256) == 0 && (K % 32) == 0 &&
      K >= 256 && (xN % 2048) == 0 && (wN % 2048) == 0) {
    unsigned short* xb = (unsigned short*)d_ws;
    unsigned short* wb = xb + (size_t)xN;
    const int nbx = xN / 2048, nbw = wN / 2048;
    cvt_fused<<<nbx + nbw, 256, 0, stream>>>((const float4*)x, (const int4*)wq,
                                             (ushort4*)xb, (ushort4*)wb, nbx);
    const int nwg = (M / 256) * (N / 256);
    gemm256_bt_bf16<<<nwg, 512, 0, stream>>>(xb, wb, scale, bias, y, M, N, K);
  } else {
    dim3 grid((N + 255) / 256, M);
    naive_kernel<<<grid, 256, 0, stream>>>(x, wq, scale, bias, y, M, N, K);
  }
}